// Round 7
// baseline (262.941 us; speedup 1.0000x reference)
//
#include <hip/hip_runtime.h>

// int4-dequant GEMM: y[m,n] = sum_k x[m,k] * scale[n, k/128] * (q[n,k] - 8)
// x: (512,4096) f32 | weight_packed: (11008,2048) int32 (2 nibbles in low byte) |
// scales: (11008,32) f32 | out: (512,11008) f32
//
// R14: occupancy attack. Evidence: R7..R13 all pinned at 101-155us with
// MfmaUtil 12-18 / VALU 19-31 / Occ 14-16 — every variant used ~256 regs/wave
// (128 AGPR acc + ~128 VGPR) -> 2 waves/SIMD -> the ds_read->dequant->MFMA
// chain is latency-exposed; schedule tweaks (1-barrier R9, DMA+counted-vmcnt
// R13) moved nothing because stall, not issue, dominates (absolute pipe time:
// MFMA 18.5us, VALU ~32us vs 108us wall).
// Design: wave-tile 64x32 -> acc[2] = 32 AGPR; producer-side dequant (VALU
// once/elem, R7-proven); A direct from verified fragment-layout xw (no A-LDS);
// B LDS 9.2KB single-buffer. ~90 regs/wave under launch_bounds(256,4) ->
// >=16 waves/CU (2x R13), possibly 20. BM=128 BN=64 -> grid 688, KS=1,
// ALL blocks co-resident: no partials, no reduce_k (-13us, -67MB), no tail.
// Schedule: R7/R12's proven 2-barrier with full-iter pbr/sc prefetch and
// 1-step A prefetch (explicit aA/aB alternation, static indices).
// Verified pieces preserved: dequant math, 16B@144B-stride 0-conflict sB
// pattern (R5/R7 measured), 32x32x16 C/D mapping
// (col=lane&31, row=(r&3)+8*(r>>2)+4*(lane>>5)), fragment-layout cvt_x.
// Spill tripwire: VGPR_Count must be <=128 and WRITE_SIZE exactly 22016 KB.

typedef __attribute__((ext_vector_type(8)))  short short8;   // 32x32x16 A/B frag
typedef __attribute__((ext_vector_type(16))) float f32x16;   // 32x32x16 C/D frag
typedef __attribute__((ext_vector_type(4)))  float f32x4;
typedef __attribute__((ext_vector_type(4)))  int   i32x4;
typedef __attribute__((ext_vector_type(2)))  int   i32x2;

#define M_DIM 512
#define N_DIM 11008
#define K_DIM 4096
#define BM 128
#define BN 64
#define BK 64
#define THREADS 256
#define NTILE_M (M_DIM / BM)        // 4
#define NTILE_N (N_DIM / BN)        // 172
#define NTILES  (NTILE_M * NTILE_N) // 688 = 8 XCDs * 86
#define KITERS  (K_DIM / BK)        // 64
#define KB16    (K_DIM / 16)        // 256 k-subtiles per 32-row m-stripe

#if defined(__has_builtin)
#  if __has_builtin(__builtin_amdgcn_cvt_pk_bf16_f32)
#    define HAVE_PK_BF16 1
#  endif
#endif
#ifndef HAVE_PK_BF16
#  define HAVE_PK_BF16 0
#endif

__device__ __forceinline__ unsigned int fbits(float f) {
    union { float f; unsigned int u; } c; c.f = f; return c.u;
}
__device__ __forceinline__ int pack2bf(float lo, float hi) {  // [hi|lo] bf16, RNE
#if HAVE_PK_BF16
    typedef __attribute__((ext_vector_type(2))) __bf16 bf16x2;
    bf16x2 p = __builtin_amdgcn_cvt_pk_bf16_f32(lo, hi);
    int r; __builtin_memcpy(&r, &p, 4);
    return r;
#else
    unsigned int ul = fbits(lo), uh = fbits(hi);
    unsigned int l = (ul + 0x7FFFu + ((ul >> 16) & 1u)) >> 16;
    unsigned int h = (uh + 0x7FFFu + ((uh >> 16) & 1u)) & 0xFFFF0000u;
    return (int)(h | l);
#endif
}

// ---- x f32 -> bf16 fragment-layout workspace (verified R10/R12/R13) ----
// chunk c in [0, M*K/8): lane=c&63, kb16=(c>>6)&255, mb=c>>14
// m = mb*32 + (lane&31), k = kb16*16 + (lane>>5)*8
__global__ __launch_bounds__(THREADS)
void cvt_x(const float* __restrict__ x, unsigned short* __restrict__ xw)
{
    int c    = blockIdx.x * THREADS + threadIdx.x;
    int lane = c & 63;
    int kb   = (c >> 6) & (KB16 - 1);
    int mb   = c >> 14;
    int m    = mb * 32 + (lane & 31);
    int k    = kb * 16 + (lane >> 5) * 8;

    const float* src = x + (size_t)m * K_DIM + k;
    f32x4 v0 = *(const f32x4*)(src);
    f32x4 v1 = *(const f32x4*)(src + 4);
    i32x4 p;
    p[0] = pack2bf(v0[0], v0[1]);
    p[1] = pack2bf(v0[2], v0[3]);
    p[2] = pack2bf(v1[0], v1[1]);
    p[3] = pack2bf(v1[2], v1[3]);
    *(i32x4*)(xw + (size_t)c * 8) = p;
}

// ---- main GEMM: 128x64 tile, 4 waves of 64x32, 32x32x16 MFMA, KS=1 ----
template<bool PRECVT>
__global__ __launch_bounds__(THREADS, 4)
void dq_gemm(const unsigned short* __restrict__ xw,
             const float* __restrict__ xf,
             const int* __restrict__ wp,
             const float* __restrict__ scales,
             float* __restrict__ out)
{
    // dequantized B tile: 64 rows x (64+8) bf16 = 9.2 KB single buffer.
    // 16B chunks at 144B row stride: R5/R7-measured 0-conflict pattern.
    __shared__ __align__(16) unsigned short sB[BN][BK + 8];

    const int t  = threadIdx.x;
    const int bx = blockIdx.x;

    // Bijective XCD-grouped mapping (R11-style): xcd = bx&7 (dispatch
    // round-robins %8), w = bx>>3 in [0,86); G = xcd*86 + w in [0,688).
    // nb = G>>2, m_idx = G&3: each n-panel's 4 m-blocks land on ONE XCD
    // (512 KB weight panel reused 4x in that XCD's L2).
    const int G     = (bx & 7) * 86 + (bx >> 3);
    const int nb    = G >> 2;
    const int m_idx = G & 3;

    const int m0 = m_idx * BM;
    const int n0 = nb * BN;

    const int wave = t >> 6;
    const int lane = t & 63;
    const int wm = (wave & 1) * 64;    // 2 m-waves
    const int wn = (wave >> 1) * 32;   // 2 n-waves
    const int lr = lane & 31;          // frag row
    const int hi = lane >> 5;          // k-half selector
    const int lk = hi * 8;             // frag k offset (shorts)

    // B staging decomposition: 64 rows x 32 ints = 512 chunks of 16B,
    // chunk c = i*256 + t (i in 0..1): row = c>>3, intcol = (c&7)*4.
    const int tr3 = t >> 3;            // row base within 32-row stripe
    const int tu4 = (t & 7) * 4;       // int col of 16B chunk

    // per-thread 32-bit offsets (all fit int)
    const int wrow = (n0 + tr3) * (K_DIM / 2) + tu4;
    const int srow = (n0 + tr3) * (K_DIM / 128);

    i32x4 pbr[2];
    float sc[2];

    auto LOADB = [&](int kk) {
        const int w0 = kk * (BK / 2);
        pbr[0] = *(const i32x4*)(wp + wrow + w0);
        pbr[1] = *(const i32x4*)(wp + wrow + 32 * (K_DIM / 2) + w0);
        sc[0] = scales[srow + (kk >> 1)];
        sc[1] = scales[srow + 32 * (K_DIM / 128) + (kk >> 1)];
    };

    auto WRITEB = [&]() {
        #pragma unroll
        for (int i = 0; i < 2; ++i) {
            const float s = sc[i], ns8 = s * -8.0f;
            i32x4 res;
            #pragma unroll
            for (int e = 0; e < 4; ++e) {
                int b = pbr[i][e];
                res[e] = pack2bf((float)(b & 15) * s + ns8,
                                 (float)((b >> 4) & 15) * s + ns8);
            }
            *(i32x4*)&sB[i * 32 + tr3][tu4 * 2] = res;
        }
    };

    // A fragments: direct from fragment-layout xw (no LDS, L2/L1-resident).
    const short8* xa8 = (const short8*)xw;
    const int mb0 = (m0 + wm) >> 5;
    const int ab0 = (mb0 * KB16) * 64 + lane;
    const int ab1 = ((mb0 + 1) * KB16) * 64 + lane;

    auto LOADA = [&](int kk, int s4, short8 (&dst)[2]) {
        if constexpr (PRECVT) {
            const int kadd = (kk * 4 + s4) * 64;
            dst[0] = xa8[ab0 + kadd];
            dst[1] = xa8[ab1 + kadd];
        } else {
            #pragma unroll
            for (int i = 0; i < 2; ++i) {
                const float* src = xf + (size_t)(m0 + wm + i * 32 + lr) * K_DIM
                                      + kk * BK + s4 * 16 + lk;
                f32x4 v0 = *(const f32x4*)(src);
                f32x4 v1 = *(const f32x4*)(src + 4);
                i32x4 p;
                p[0] = pack2bf(v0[0], v0[1]);
                p[1] = pack2bf(v0[2], v0[3]);
                p[2] = pack2bf(v1[0], v1[1]);
                p[3] = pack2bf(v1[2], v1[3]);
                __builtin_memcpy(&dst[i], &p, 16);
            }
        }
    };

    f32x16 acc[2] = {};
    short8 aA[2], aB[2];

    auto MFMA2 = [&](const short8 (&a)[2], int s4) {
        const short8 b = *(const short8*)&sB[wn + lr][s4 * 16 + lk];
        acc[0] = __builtin_amdgcn_mfma_f32_32x32x16_bf16(a[0], b, acc[0], 0, 0, 0);
        acc[1] = __builtin_amdgcn_mfma_f32_32x32x16_bf16(a[1], b, acc[1], 0, 0, 0);
    };

    // prologue: full-iter B prefetch + 1-step A prefetch
    LOADB(0);
    LOADA(0, 0, aA);

    for (int kk = 0; kk < KITERS; ++kk) {
        WRITEB();                    // dequant pbr(kk) -> sB (uses sc(kk))
        __syncthreads();             // sB ready
        if (kk + 1 < KITERS)
            LOADB(kk + 1);           // in flight across the whole MFMA phase

        // s4 pipeline: explicit aA/aB alternation, all-static indices
        LOADA(kk, 1, aB);  MFMA2(aA, 0);
        LOADA(kk, 2, aA);  MFMA2(aB, 1);
        LOADA(kk, 3, aB);  MFMA2(aA, 2);
        if (kk + 1 < KITERS) LOADA(kk + 1, 0, aA);
        MFMA2(aB, 3);

        __syncthreads();             // all waves done reading sB
    }

    // direct store: C/D col=lane&31, row=(r&3)+8*(r>>2)+4*(lane>>5)
    const int rbase = hi * 4;
    #pragma unroll
    for (int i = 0; i < 2; ++i) {
        const int mg0 = m0 + wm + i * 32 + rbase;
        const int ng  = n0 + wn + lr;
        #pragma unroll
        for (int r = 0; r < 16; ++r)
            out[(size_t)(mg0 + (r & 3) + 8 * (r >> 2)) * N_DIM + ng] = acc[i][r];
    }
}

extern "C" void kernel_launch(void* const* d_in, const int* in_sizes, int n_in,
                              void* d_out, int out_size, void* d_ws, size_t ws_size,
                              hipStream_t stream) {
    (void)in_sizes; (void)n_in; (void)out_size;
    const float* x      = (const float*)d_in[0];
    const int*   wpck   = (const int*)d_in[1];
    const float* scales = (const float*)d_in[2];
    float*       out    = (float*)d_out;

    const size_t XW_BYTES = (size_t)M_DIM * K_DIM * 2;   // 4 MB

    if (ws_size >= XW_BYTES) {
        unsigned short* xw = (unsigned short*)d_ws;
        cvt_x<<<(M_DIM * K_DIM) / (THREADS * 8), THREADS, 0, stream>>>(x, xw);
        dq_gemm<true><<<NTILES, THREADS, 0, stream>>>(xw, x, wpck, scales, out);
    } else {
        dq_gemm<false><<<NTILES, THREADS, 0, stream>>>(nullptr, x, wpck, scales, out);
    }
}